// Round 1
// baseline (865.008 us; speedup 1.0000x reference)
//
#include <hip/hip_runtime.h>
#include <hip/hip_bf16.h>
#include <math.h>
#include <stdint.h>

#define NEG_SLOPE 0.2f
#define BN_EPS 1e-5f

// ---------------------------------------------------------------------------
// BN constant prep: scale = gamma*rsqrt(var+eps), shift = beta - mean*scale
// ---------------------------------------------------------------------------
__global__ __launch_bounds__(128) void bn_prep(const float* __restrict__ gamma,
                                               const float* __restrict__ beta,
                                               const float* __restrict__ rmean,
                                               const float* __restrict__ rvar,
                                               float* __restrict__ scale,
                                               float* __restrict__ shift) {
    int c = threadIdx.x;
    float s = gamma[c] * rsqrtf(rvar[c] + BN_EPS);
    scale[c] = s;
    shift[c] = beta[c] - rmean[c] * s;
}

// ---------------------------------------------------------------------------
// CSR build
// ---------------------------------------------------------------------------
__global__ __launch_bounds__(256) void count_deg(const int* __restrict__ dst,
                                                 int* __restrict__ deg, int E) {
    int i = blockIdx.x * 256 + threadIdx.x;
    if (i < E) atomicAdd(&deg[dst[i]], 1);
}

__global__ __launch_bounds__(1024) void scan_offsets(const int* __restrict__ deg,
                                                     int* __restrict__ off, int N) {
    __shared__ int sums[1024];
    int tid = threadIdx.x;
    int chunk = (N + 1023) / 1024;
    int start = tid * chunk;
    int end = start + chunk; if (end > N) end = N;
    int s = 0;
    for (int i = start; i < end; ++i) s += deg[i];
    sums[tid] = s;
    __syncthreads();
    // Hillis-Steele inclusive scan
    for (int d = 1; d < 1024; d <<= 1) {
        int v = (tid >= d) ? sums[tid - d] : 0;
        __syncthreads();
        sums[tid] += v;
        __syncthreads();
    }
    int run = (tid == 0) ? 0 : sums[tid - 1];
    for (int i = start; i < end; ++i) { off[i] = run; run += deg[i]; }
    if (tid == 1023) off[N] = run;  // == E
}

__global__ __launch_bounds__(256) void fill_csr(const int* __restrict__ src,
                                                const int* __restrict__ dst,
                                                const int* __restrict__ off,
                                                int* __restrict__ cursor,
                                                int* __restrict__ csr_src, int E) {
    int i = blockIdx.x * 256 + threadIdx.x;
    if (i < E) {
        int d = dst[i];
        int p = atomicAdd(&cursor[d], 1);
        csr_src[off[d] + p] = src[i];
    }
}

// ---------------------------------------------------------------------------
// H = X @ W  (N x 128) @ (128 x 128), W staged in LDS, 8 rows per block-iter,
// 4 rows per thread (amortizes the W LDS read over 4 FMAs).
// ---------------------------------------------------------------------------
__global__ __launch_bounds__(256) void gemm_x128(const float* __restrict__ X,
                                                 const float* __restrict__ W,
                                                 float* __restrict__ H, int N) {
    __shared__ float sW[128 * 128];
    __shared__ __align__(16) float sxT[128][8];  // [k][row]
    for (int i = threadIdx.x; i < 128 * 128; i += 256) sW[i] = W[i];
    int j = threadIdx.x & 127;
    int rg = threadIdx.x >> 7;  // 0/1 -> rows rg*4 .. rg*4+3
    for (int row0 = blockIdx.x * 8; row0 < N; row0 += gridDim.x * 8) {
        __syncthreads();  // protect sxT from prev iter readers (also fences W load 1st iter)
#pragma unroll
        for (int r = rg * 4; r < rg * 4 + 4; ++r) {
            int row = row0 + r;
            sxT[j][r] = (row < N) ? X[row * 128 + j] : 0.f;
        }
        __syncthreads();
        float acc0 = 0.f, acc1 = 0.f, acc2 = 0.f, acc3 = 0.f;
#pragma unroll 4
        for (int k = 0; k < 128; ++k) {
            float w = sW[k * 128 + j];
            float4 xv = *(const float4*)&sxT[k][rg * 4];
            acc0 = fmaf(xv.x, w, acc0);
            acc1 = fmaf(xv.y, w, acc1);
            acc2 = fmaf(xv.z, w, acc2);
            acc3 = fmaf(xv.w, w, acc3);
        }
        int row = row0 + rg * 4;
        if (row + 0 < N) H[(row + 0) * 128 + j] = acc0;
        if (row + 1 < N) H[(row + 1) * 128 + j] = acc1;
        if (row + 2 < N) H[(row + 2) * 128 + j] = acc2;
        if (row + 3 < N) H[(row + 3) * 128 + j] = acc3;
    }
}

// ---------------------------------------------------------------------------
// s_src[n] = h[n,:]·a_src ; s_dst[n] = h[n,:]·a_dst   (one wave per node)
// ---------------------------------------------------------------------------
__global__ __launch_bounds__(256) void node_scores(const float* __restrict__ H,
                                                   const float* __restrict__ a_src,
                                                   const float* __restrict__ a_dst,
                                                   float* __restrict__ s_src,
                                                   float* __restrict__ s_dst, int N) {
    int node = blockIdx.x * 4 + (threadIdx.x >> 6);
    if (node >= N) return;
    int lane = threadIdx.x & 63;
    float2 hv = *(const float2*)&H[node * 128 + lane * 2];
    float2 as = *(const float2*)&a_src[lane * 2];
    float2 ad = *(const float2*)&a_dst[lane * 2];
    float vs = hv.x * as.x + hv.y * as.y;
    float vd = hv.x * ad.x + hv.y * ad.y;
#pragma unroll
    for (int off = 32; off; off >>= 1) {
        vs += __shfl_down(vs, off);
        vd += __shfl_down(vd, off);
    }
    if (lane == 0) { s_src[node] = vs; s_dst[node] = vd; }
}

// ---------------------------------------------------------------------------
// Per-dst-node softmax aggregation. One wave per node; lane = 2 channels.
// out[n,:] = (sum_e w_e * h[src_e,:]) / (sum_e w_e + 1e-16) + bias
// optional fused BN(eval) + ReLU epilogue.
// ---------------------------------------------------------------------------
__global__ __launch_bounds__(256) void gat_aggregate(const float* __restrict__ H,
                                                     const int* __restrict__ off,
                                                     const int* __restrict__ csr_src,
                                                     const float* __restrict__ s_src,
                                                     const float* __restrict__ s_dst,
                                                     const float* __restrict__ bias,
                                                     const float* __restrict__ bn_scale,
                                                     const float* __restrict__ bn_shift,
                                                     int do_bn_relu,
                                                     float* __restrict__ out, int N) {
    int node = blockIdx.x * 4 + (threadIdx.x >> 6);
    if (node >= N) return;
    int lane = threadIdx.x & 63;
    int beg = off[node], end = off[node + 1];
    float sd = s_dst[node];

    // pass 1: max over edges (lanes parallelize over edges)
    float m = -INFINITY;
    for (int i = beg + lane; i < end; i += 64) {
        float e = s_src[csr_src[i]] + sd;
        e = (e >= 0.f) ? e : NEG_SLOPE * e;
        m = fmaxf(m, e);
    }
#pragma unroll
    for (int o = 32; o; o >>= 1) m = fmaxf(m, __shfl_xor(m, o));
    // (no-edge nodes: m stays -inf but loop below is empty -> out = bias)

    // pass 2: weighted sum (lanes = channels, scalar part redundant per lane)
    int c0 = lane * 2;
    float sumw = 0.f, accx = 0.f, accy = 0.f;
    for (int i = beg; i < end; ++i) {
        int s = csr_src[i];
        float e = s_src[s] + sd;
        e = (e >= 0.f) ? e : NEG_SLOPE * e;
        float w = expf(e - m);
        sumw += w;
        float2 hv = *(const float2*)&H[s * 128 + c0];
        accx = fmaf(w, hv.x, accx);
        accy = fmaf(w, hv.y, accy);
    }
    float inv = 1.f / (sumw + 1e-16f);
    float o0 = accx * inv + bias[c0];
    float o1 = accy * inv + bias[c0 + 1];
    if (do_bn_relu) {
        o0 = fmaxf(o0 * bn_scale[c0] + bn_shift[c0], 0.f);
        o1 = fmaxf(o1 * bn_scale[c0 + 1] + bn_shift[c0 + 1], 0.f);
    }
    out[node * 128 + c0] = o0;
    out[node * 128 + c0 + 1] = o1;
}

// ---------------------------------------------------------------------------
// Link predictor: out[q] = sigmoid( relu((x[a]*x[b]) @ Wp1 + bp1) · Wp2 + bp2 )
// Wp1 in LDS; 8 queries per block-iter, 4 per thread.
// ---------------------------------------------------------------------------
__global__ __launch_bounds__(256) void link_pred(const float* __restrict__ X,
                                                 const int* __restrict__ E0,
                                                 const int* __restrict__ E1,
                                                 const float* __restrict__ Wp1,
                                                 const float* __restrict__ bp1,
                                                 const float* __restrict__ Wp2,
                                                 const float* __restrict__ bp2_p,
                                                 float* __restrict__ out, int Q) {
    __shared__ float sW[128 * 128];
    __shared__ __align__(16) float shT[128][8];  // [k][query]
    __shared__ float sred[4][4];                 // [wave][query-in-group]
    for (int i = threadIdx.x; i < 128 * 128; i += 256) sW[i] = Wp1[i];
    int j = threadIdx.x & 127;
    int qg = threadIdx.x >> 7;  // query group 0/1 -> queries qg*4..qg*4+3
    float bj = bp1[j];
    float w2 = Wp2[j];
    float b2 = bp2_p[0];
    for (int q0 = blockIdx.x * 8; q0 < Q; q0 += gridDim.x * 8) {
        __syncthreads();  // protect shT/sred reuse (also fences sW load 1st iter)
#pragma unroll
        for (int r = qg * 4; r < qg * 4 + 4; ++r) {
            int q = q0 + r;
            float v = 0.f;
            if (q < Q) {
                int a = E0[q], b = E1[q];
                v = X[a * 128 + j] * X[b * 128 + j];
            }
            shT[j][r] = v;
        }
        __syncthreads();
        float acc0 = bj, acc1 = bj, acc2 = bj, acc3 = bj;
#pragma unroll 4
        for (int k = 0; k < 128; ++k) {
            float w = sW[k * 128 + j];
            float4 hv = *(const float4*)&shT[k][qg * 4];
            acc0 = fmaf(hv.x, w, acc0);
            acc1 = fmaf(hv.y, w, acc1);
            acc2 = fmaf(hv.z, w, acc2);
            acc3 = fmaf(hv.w, w, acc3);
        }
        float p0 = fmaxf(acc0, 0.f) * w2;
        float p1 = fmaxf(acc1, 0.f) * w2;
        float p2 = fmaxf(acc2, 0.f) * w2;
        float p3 = fmaxf(acc3, 0.f) * w2;
#pragma unroll
        for (int o = 32; o; o >>= 1) {
            p0 += __shfl_down(p0, o);
            p1 += __shfl_down(p1, o);
            p2 += __shfl_down(p2, o);
            p3 += __shfl_down(p3, o);
        }
        int wave = threadIdx.x >> 6;
        if ((threadIdx.x & 63) == 0) {
            sred[wave][0] = p0; sred[wave][1] = p1;
            sred[wave][2] = p2; sred[wave][3] = p3;
        }
        __syncthreads();
        if (threadIdx.x < 8) {
            int g = threadIdx.x >> 2, i = threadIdx.x & 3;
            int q = q0 + g * 4 + i;
            if (q < Q) {
                float z = sred[2 * g][i] + sred[2 * g + 1][i] + b2;
                out[q] = 1.f / (1.f + expf(-z));
            }
        }
    }
}

// ---------------------------------------------------------------------------
extern "C" void kernel_launch(void* const* d_in, const int* in_sizes, int n_in,
                              void* d_out, int out_size, void* d_ws, size_t ws_size,
                              hipStream_t stream) {
    const float* emb    = (const float*)d_in[0];
    const float* W1     = (const float*)d_in[1];
    const float* a_src1 = (const float*)d_in[2];
    const float* a_dst1 = (const float*)d_in[3];
    const float* b1     = (const float*)d_in[4];
    const float* gamma  = (const float*)d_in[5];
    const float* beta   = (const float*)d_in[6];
    const float* rmean  = (const float*)d_in[7];
    const float* rvar   = (const float*)d_in[8];
    const float* W2     = (const float*)d_in[9];
    const float* a_src2 = (const float*)d_in[10];
    const float* a_dst2 = (const float*)d_in[11];
    const float* b2     = (const float*)d_in[12];
    const float* Wp1    = (const float*)d_in[13];
    const float* bp1    = (const float*)d_in[14];
    const float* Wp2    = (const float*)d_in[15];
    const float* bp2    = (const float*)d_in[16];
    const int* edge_index = (const int*)d_in[17];
    const int* edges      = (const int*)d_in[18];

    const int N = in_sizes[0] / 128;
    const int E = in_sizes[17] / 2;
    const int Q = in_sizes[18] / 2;
    const int* src = edge_index;
    const int* dst = edge_index + E;
    const int* e0 = edges;
    const int* e1 = edges + Q;
    float* out = (float*)d_out;

    // workspace carve-up (256B-aligned chunks)
    uintptr_t base = (uintptr_t)d_ws;
    size_t cur = 0;
    auto take = [&](size_t bytes) -> void* {
        void* p = (void*)(base + cur);
        cur += (bytes + 255) & ~(size_t)255;
        return p;
    };
    float* bufA   = (float*)take((size_t)N * 128 * 4);  // h1, then h2
    float* bufB   = (float*)take((size_t)N * 128 * 4);  // x1, then x2
    float* s_src  = (float*)take((size_t)N * 4);
    float* s_dst  = (float*)take((size_t)N * 4);
    float* bnsc   = (float*)take(128 * 4);
    float* bnsh   = (float*)take(128 * 4);
    int*   deg    = (int*)take((size_t)N * 4);
    int*   cursor = (int*)take((size_t)N * 4);
    int*   offs   = (int*)take((size_t)(N + 1) * 4);
    int*   csr    = (int*)take((size_t)E * 4);
    (void)ws_size; (void)n_in; (void)out_size;

    hipMemsetAsync(deg, 0, (size_t)N * 4, stream);
    hipMemsetAsync(cursor, 0, (size_t)N * 4, stream);

    bn_prep<<<1, 128, 0, stream>>>(gamma, beta, rmean, rvar, bnsc, bnsh);

    // CSR by dst (graph identical for both conv layers)
    count_deg<<<(E + 255) / 256, 256, 0, stream>>>(dst, deg, E);
    scan_offsets<<<1, 1024, 0, stream>>>(deg, offs, N);
    fill_csr<<<(E + 255) / 256, 256, 0, stream>>>(src, dst, offs, cursor, csr, E);

    // ---- conv1 + BN + ReLU ----
    gemm_x128<<<512, 256, 0, stream>>>(emb, W1, bufA, N);
    node_scores<<<(N + 3) / 4, 256, 0, stream>>>(bufA, a_src1, a_dst1, s_src, s_dst, N);
    gat_aggregate<<<(N + 3) / 4, 256, 0, stream>>>(bufA, offs, csr, s_src, s_dst, b1,
                                                   bnsc, bnsh, 1, bufB, N);
    // ---- conv2 ----
    gemm_x128<<<512, 256, 0, stream>>>(bufB, W2, bufA, N);
    node_scores<<<(N + 3) / 4, 256, 0, stream>>>(bufA, a_src2, a_dst2, s_src, s_dst, N);
    gat_aggregate<<<(N + 3) / 4, 256, 0, stream>>>(bufA, offs, csr, s_src, s_dst, b2,
                                                   nullptr, nullptr, 0, bufB, N);
    // ---- link predictor ----
    link_pred<<<512, 256, 0, stream>>>(bufB, e0, e1, Wp1, bp1, Wp2, bp2, out, Q);
}

// Round 2
// 648.888 us; speedup vs baseline: 1.3331x; 1.3331x over previous
//
#include <hip/hip_runtime.h>
#include <hip/hip_bf16.h>
#include <math.h>
#include <stdint.h>

#define NEG_SLOPE 0.2f
#define BN_EPS 1e-5f

typedef __attribute__((ext_vector_type(8))) short short8;
typedef __attribute__((ext_vector_type(4))) float float4v;

static __device__ __forceinline__ unsigned short f2bf(float f) {
    union { float f; unsigned u; } v; v.f = f;
    unsigned r = (v.u + 0x7fffu + ((v.u >> 16) & 1u)) >> 16;  // RNE
    return (unsigned short)r;
}

// ---------------------------------------------------------------------------
// BN constant prep: scale = gamma*rsqrt(var+eps), shift = beta - mean*scale
// ---------------------------------------------------------------------------
__global__ __launch_bounds__(128) void bn_prep(const float* __restrict__ gamma,
                                               const float* __restrict__ beta,
                                               const float* __restrict__ rmean,
                                               const float* __restrict__ rvar,
                                               float* __restrict__ scale,
                                               float* __restrict__ shift) {
    int c = threadIdx.x;
    float s = gamma[c] * rsqrtf(rvar[c] + BN_EPS);
    scale[c] = s;
    shift[c] = beta[c] - rmean[c] * s;
}

// ---------------------------------------------------------------------------
// one-time: WTg[n*128+k] = bf16(Wp1[k*128+n])   (pre-transposed B for MFMA)
// ---------------------------------------------------------------------------
__global__ __launch_bounds__(256) void wp1_to_bf16T(const float* __restrict__ Wp1,
                                                    unsigned short* __restrict__ WTg) {
    int idx = blockIdx.x * 256 + threadIdx.x;  // 16384 total
    int k = idx >> 7, n = idx & 127;
    WTg[n * 128 + k] = f2bf(Wp1[idx]);
}

// ---------------------------------------------------------------------------
// CSR build
// ---------------------------------------------------------------------------
__global__ __launch_bounds__(256) void count_deg(const int* __restrict__ dst,
                                                 int* __restrict__ deg, int E) {
    int i = blockIdx.x * 256 + threadIdx.x;
    if (i < E) atomicAdd(&deg[dst[i]], 1);
}

__global__ __launch_bounds__(1024) void scan_offsets(const int* __restrict__ deg,
                                                     int* __restrict__ off, int N) {
    __shared__ int sums[1024];
    int tid = threadIdx.x;
    int chunk = (N + 1023) / 1024;
    int start = tid * chunk;
    int end = start + chunk; if (end > N) end = N;
    int s = 0;
    for (int i = start; i < end; ++i) s += deg[i];
    sums[tid] = s;
    __syncthreads();
    for (int d = 1; d < 1024; d <<= 1) {
        int v = (tid >= d) ? sums[tid - d] : 0;
        __syncthreads();
        sums[tid] += v;
        __syncthreads();
    }
    int run = (tid == 0) ? 0 : sums[tid - 1];
    for (int i = start; i < end; ++i) { off[i] = run; run += deg[i]; }
    if (tid == 1023) off[N] = run;  // == E
}

__global__ __launch_bounds__(256) void fill_csr(const int* __restrict__ src,
                                                const int* __restrict__ dst,
                                                const int* __restrict__ off,
                                                int* __restrict__ cursor,
                                                int* __restrict__ csr_src, int E) {
    int i = blockIdx.x * 256 + threadIdx.x;
    if (i < E) {
        int d = dst[i];
        int p = atomicAdd(&cursor[d], 1);
        csr_src[off[d] + p] = src[i];
    }
}

// ---------------------------------------------------------------------------
// H = X @ W  (N x 128) @ (128 x 128), fp32, W staged in LDS
// ---------------------------------------------------------------------------
__global__ __launch_bounds__(256) void gemm_x128(const float* __restrict__ X,
                                                 const float* __restrict__ W,
                                                 float* __restrict__ H, int N) {
    __shared__ float sW[128 * 128];
    __shared__ __align__(16) float sxT[128][8];  // [k][row]
    for (int i = threadIdx.x; i < 128 * 128; i += 256) sW[i] = W[i];
    int j = threadIdx.x & 127;
    int rg = threadIdx.x >> 7;
    for (int row0 = blockIdx.x * 8; row0 < N; row0 += gridDim.x * 8) {
        __syncthreads();
#pragma unroll
        for (int r = rg * 4; r < rg * 4 + 4; ++r) {
            int row = row0 + r;
            sxT[j][r] = (row < N) ? X[row * 128 + j] : 0.f;
        }
        __syncthreads();
        float acc0 = 0.f, acc1 = 0.f, acc2 = 0.f, acc3 = 0.f;
#pragma unroll 4
        for (int k = 0; k < 128; ++k) {
            float w = sW[k * 128 + j];
            float4 xv = *(const float4*)&sxT[k][rg * 4];
            acc0 = fmaf(xv.x, w, acc0);
            acc1 = fmaf(xv.y, w, acc1);
            acc2 = fmaf(xv.z, w, acc2);
            acc3 = fmaf(xv.w, w, acc3);
        }
        int row = row0 + rg * 4;
        if (row + 0 < N) H[(row + 0) * 128 + j] = acc0;
        if (row + 1 < N) H[(row + 1) * 128 + j] = acc1;
        if (row + 2 < N) H[(row + 2) * 128 + j] = acc2;
        if (row + 3 < N) H[(row + 3) * 128 + j] = acc3;
    }
}

// ---------------------------------------------------------------------------
// s_src[n] = h[n,:]·a_src ; s_dst[n] = h[n,:]·a_dst   (one wave per node)
// ---------------------------------------------------------------------------
__global__ __launch_bounds__(256) void node_scores(const float* __restrict__ H,
                                                   const float* __restrict__ a_src,
                                                   const float* __restrict__ a_dst,
                                                   float* __restrict__ s_src,
                                                   float* __restrict__ s_dst, int N) {
    int node = blockIdx.x * 4 + (threadIdx.x >> 6);
    if (node >= N) return;
    int lane = threadIdx.x & 63;
    float2 hv = *(const float2*)&H[node * 128 + lane * 2];
    float2 as = *(const float2*)&a_src[lane * 2];
    float2 ad = *(const float2*)&a_dst[lane * 2];
    float vs = hv.x * as.x + hv.y * as.y;
    float vd = hv.x * ad.x + hv.y * ad.y;
#pragma unroll
    for (int off = 32; off; off >>= 1) {
        vs += __shfl_down(vs, off);
        vd += __shfl_down(vd, off);
    }
    if (lane == 0) { s_src[node] = vs; s_dst[node] = vd; }
}

// ---------------------------------------------------------------------------
// Per-dst-node softmax aggregation. One wave per node; lane = 2 channels.
// ---------------------------------------------------------------------------
__global__ __launch_bounds__(256) void gat_aggregate(const float* __restrict__ H,
                                                     const int* __restrict__ off,
                                                     const int* __restrict__ csr_src,
                                                     const float* __restrict__ s_src,
                                                     const float* __restrict__ s_dst,
                                                     const float* __restrict__ bias,
                                                     const float* __restrict__ bn_scale,
                                                     const float* __restrict__ bn_shift,
                                                     int do_bn_relu,
                                                     float* __restrict__ out, int N) {
    int node = blockIdx.x * 4 + (threadIdx.x >> 6);
    if (node >= N) return;
    int lane = threadIdx.x & 63;
    int beg = off[node], end = off[node + 1];
    float sd = s_dst[node];

    float m = -INFINITY;
    for (int i = beg + lane; i < end; i += 64) {
        float e = s_src[csr_src[i]] + sd;
        e = (e >= 0.f) ? e : NEG_SLOPE * e;
        m = fmaxf(m, e);
    }
#pragma unroll
    for (int o = 32; o; o >>= 1) m = fmaxf(m, __shfl_xor(m, o));

    int c0 = lane * 2;
    float sumw = 0.f, accx = 0.f, accy = 0.f;
    for (int i = beg; i < end; ++i) {
        int s = csr_src[i];
        float e = s_src[s] + sd;
        e = (e >= 0.f) ? e : NEG_SLOPE * e;
        float w = expf(e - m);
        sumw += w;
        float2 hv = *(const float2*)&H[s * 128 + c0];
        accx = fmaf(w, hv.x, accx);
        accy = fmaf(w, hv.y, accy);
    }
    float inv = 1.f / (sumw + 1e-16f);
    float o0 = accx * inv + bias[c0];
    float o1 = accy * inv + bias[c0 + 1];
    if (do_bn_relu) {
        o0 = fmaxf(o0 * bn_scale[c0] + bn_shift[c0], 0.f);
        o1 = fmaxf(o1 * bn_scale[c0 + 1] + bn_shift[c0 + 1], 0.f);
    }
    out[node * 128 + c0] = o0;
    out[node * 128 + c0 + 1] = o1;
}

// ---------------------------------------------------------------------------
// Link predictor, MFMA bf16:
// out[q] = sigmoid( relu((x[a]∘x[b]) @ Wp1 + bp1) · Wp2 + bp2 )
// 128 queries/block; 4 waves × 2 M-tiles (16x16x32 bf16); epilogue fused.
// LDS rows padded to 272 B (17×16 B): fragment b128 reads ~2-way (free).
// ---------------------------------------------------------------------------
#define LP_RS 136  // row stride in bf16 elements (272 bytes)

__global__ __launch_bounds__(256) void link_pred_mfma(
    const float* __restrict__ X,
    const int* __restrict__ E0, const int* __restrict__ E1,
    const unsigned short* __restrict__ WTg,  // [128][128] bf16, WTg[n][k]
    const float* __restrict__ bp1,
    const float* __restrict__ Wp2,
    const float* __restrict__ bp2_p,
    float* __restrict__ out, int Q)
{
    __shared__ unsigned short sA[128 * LP_RS];  // h tile, row-major [query][k]
    __shared__ unsigned short sW[128 * LP_RS];  // Wp1^T   [n][k]
    int tid = threadIdx.x;
    int q0 = blockIdx.x * 128;

    // stage Wp1^T (straight copy, conflict-free)
#pragma unroll
    for (int it = 0; it < 8; ++it) {
        int idx = it * 2048 + tid * 8;  // 8 bf16 = 16 B per thread
        int n = idx >> 7, k = idx & 127;
        *(short8*)&sW[n * LP_RS + k] = *(const short8*)&WTg[idx];
    }
    // stage A = bf16(x[a] * x[b]) for 128 queries
#pragma unroll
    for (int it = 0; it < 16; ++it) {
        int r = it * 8 + (tid >> 5);
        int c = (tid & 31) * 4;
        int q = q0 + r;
        float4 p = make_float4(0.f, 0.f, 0.f, 0.f);
        if (q < Q) {
            int a = E0[q], b = E1[q];
            float4 xa = *(const float4*)&X[(size_t)a * 128 + c];
            float4 xb = *(const float4*)&X[(size_t)b * 128 + c];
            p.x = xa.x * xb.x; p.y = xa.y * xb.y;
            p.z = xa.z * xb.z; p.w = xa.w * xb.w;
        }
        ushort4 u;
        u.x = f2bf(p.x); u.y = f2bf(p.y); u.z = f2bf(p.z); u.w = f2bf(p.w);
        *(ushort4*)&sA[r * LP_RS + c] = u;
    }
    __syncthreads();

    int wave = tid >> 6, lane = tid & 63;
    int ln = lane & 15, quad = lane >> 4;
    int rowbase = wave * 32;  // queries q0+rowbase .. +31

    // A fragments in registers: [mtile][ktile]; A[m=ln][k=quad*8+j]
    short8 af[2][4];
#pragma unroll
    for (int m = 0; m < 2; ++m)
#pragma unroll
        for (int kt = 0; kt < 4; ++kt)
            af[m][kt] = *(const short8*)&sA[(rowbase + m * 16 + ln) * LP_RS + kt * 32 + quad * 8];

    float bias[8], w2c[8];
#pragma unroll
    for (int n = 0; n < 8; ++n) {
        bias[n] = bp1[n * 16 + ln];
        w2c[n] = Wp2[n * 16 + ln];
    }

    float4v acc[2][8];
#pragma unroll
    for (int m = 0; m < 2; ++m)
#pragma unroll
        for (int n = 0; n < 8; ++n)
            acc[m][n] = float4v{bias[n], bias[n], bias[n], bias[n]};

#pragma unroll
    for (int n = 0; n < 8; ++n) {
#pragma unroll
        for (int kt = 0; kt < 4; ++kt) {
            short8 bf = *(const short8*)&sW[(n * 16 + ln) * LP_RS + kt * 32 + quad * 8];
            acc[0][n] = __builtin_amdgcn_mfma_f32_16x16x32_bf16(af[0][kt], bf, acc[0][n], 0, 0, 0);
            acc[1][n] = __builtin_amdgcn_mfma_f32_16x16x32_bf16(af[1][kt], bf, acc[1][n], 0, 0, 0);
        }
    }

    // epilogue: relu, ·Wp2[col], row-sum over 128 cols, sigmoid
    // C/D layout: col = ln, row = quad*4 + reg
    float b2 = bp2_p[0];
#pragma unroll
    for (int m = 0; m < 2; ++m) {
        float r0 = 0.f, r1 = 0.f, r2 = 0.f, r3 = 0.f;
#pragma unroll
        for (int n = 0; n < 8; ++n) {
            float4v a = acc[m][n];
            float w = w2c[n];
            r0 += fmaxf(a.x, 0.f) * w;
            r1 += fmaxf(a.y, 0.f) * w;
            r2 += fmaxf(a.z, 0.f) * w;
            r3 += fmaxf(a.w, 0.f) * w;
        }
#pragma unroll
        for (int o = 1; o < 16; o <<= 1) {
            r0 += __shfl_xor(r0, o);
            r1 += __shfl_xor(r1, o);
            r2 += __shfl_xor(r2, o);
            r3 += __shfl_xor(r3, o);
        }
        if (ln == 0) {
            int rbase = q0 + rowbase + m * 16 + quad * 4;
            float rv[4] = {r0, r1, r2, r3};
#pragma unroll
            for (int r = 0; r < 4; ++r) {
                int q = rbase + r;
                if (q < Q) out[q] = 1.f / (1.f + expf(-(rv[r] + b2)));
            }
        }
    }
}

// ---------------------------------------------------------------------------
extern "C" void kernel_launch(void* const* d_in, const int* in_sizes, int n_in,
                              void* d_out, int out_size, void* d_ws, size_t ws_size,
                              hipStream_t stream) {
    const float* emb    = (const float*)d_in[0];
    const float* W1     = (const float*)d_in[1];
    const float* a_src1 = (const float*)d_in[2];
    const float* a_dst1 = (const float*)d_in[3];
    const float* b1     = (const float*)d_in[4];
    const float* gamma  = (const float*)d_in[5];
    const float* beta   = (const float*)d_in[6];
    const float* rmean  = (const float*)d_in[7];
    const float* rvar   = (const float*)d_in[8];
    const float* W2     = (const float*)d_in[9];
    const float* a_src2 = (const float*)d_in[10];
    const float* a_dst2 = (const float*)d_in[11];
    const float* b2     = (const float*)d_in[12];
    const float* Wp1    = (const float*)d_in[13];
    const float* bp1    = (const float*)d_in[14];
    const float* Wp2    = (const float*)d_in[15];
    const float* bp2    = (const float*)d_in[16];
    const int* edge_index = (const int*)d_in[17];
    const int* edges      = (const int*)d_in[18];

    const int N = in_sizes[0] / 128;
    const int E = in_sizes[17] / 2;
    const int Q = in_sizes[18] / 2;
    const int* src = edge_index;
    const int* dst = edge_index + E;
    const int* e0 = edges;
    const int* e1 = edges + Q;
    float* out = (float*)d_out;

    uintptr_t base = (uintptr_t)d_ws;
    size_t cur = 0;
    auto take = [&](size_t bytes) -> void* {
        void* p = (void*)(base + cur);
        cur += (bytes + 255) & ~(size_t)255;
        return p;
    };
    float* bufA   = (float*)take((size_t)N * 128 * 4);
    float* bufB   = (float*)take((size_t)N * 128 * 4);
    float* s_src  = (float*)take((size_t)N * 4);
    float* s_dst  = (float*)take((size_t)N * 4);
    float* bnsc   = (float*)take(128 * 4);
    float* bnsh   = (float*)take(128 * 4);
    int*   deg    = (int*)take((size_t)N * 4);
    int*   cursor = (int*)take((size_t)N * 4);
    int*   offs   = (int*)take((size_t)(N + 1) * 4);
    int*   csr    = (int*)take((size_t)E * 4);
    unsigned short* WTg = (unsigned short*)take(128 * 128 * 2);
    (void)ws_size; (void)n_in; (void)out_size;

    hipMemsetAsync(deg, 0, (size_t)N * 4, stream);
    hipMemsetAsync(cursor, 0, (size_t)N * 4, stream);

    bn_prep<<<1, 128, 0, stream>>>(gamma, beta, rmean, rvar, bnsc, bnsh);
    wp1_to_bf16T<<<64, 256, 0, stream>>>(Wp1, WTg);

    count_deg<<<(E + 255) / 256, 256, 0, stream>>>(dst, deg, E);
    scan_offsets<<<1, 1024, 0, stream>>>(deg, offs, N);
    fill_csr<<<(E + 255) / 256, 256, 0, stream>>>(src, dst, offs, cursor, csr, E);

    // ---- conv1 + BN + ReLU ----
    gemm_x128<<<512, 256, 0, stream>>>(emb, W1, bufA, N);
    node_scores<<<(N + 3) / 4, 256, 0, stream>>>(bufA, a_src1, a_dst1, s_src, s_dst, N);
    gat_aggregate<<<(N + 3) / 4, 256, 0, stream>>>(bufA, offs, csr, s_src, s_dst, b1,
                                                   bnsc, bnsh, 1, bufB, N);
    // ---- conv2 ----
    gemm_x128<<<512, 256, 0, stream>>>(bufB, W2, bufA, N);
    node_scores<<<(N + 3) / 4, 256, 0, stream>>>(bufA, a_src2, a_dst2, s_src, s_dst, N);
    gat_aggregate<<<(N + 3) / 4, 256, 0, stream>>>(bufA, offs, csr, s_src, s_dst, b2,
                                                   nullptr, nullptr, 0, bufB, N);
    // ---- link predictor (MFMA bf16) ----
    link_pred_mfma<<<(Q + 127) / 128, 256, 0, stream>>>(bufB, e0, e1, WTg, bp1, Wp2, bp2, out, Q);
}

// Round 3
// 491.720 us; speedup vs baseline: 1.7591x; 1.3196x over previous
//
#include <hip/hip_runtime.h>
#include <hip/hip_bf16.h>
#include <math.h>
#include <stdint.h>

#define NEG_SLOPE 0.2f
#define BN_EPS 1e-5f

typedef __attribute__((ext_vector_type(8))) short short8;
typedef __attribute__((ext_vector_type(4))) float float4v;

static __device__ __forceinline__ unsigned short f2bf(float f) {
    union { float f; unsigned u; } v; v.f = f;
    unsigned r = (v.u + 0x7fffu + ((v.u >> 16) & 1u)) >> 16;  // RNE
    return (unsigned short)r;
}

// ---------------------------------------------------------------------------
// BN constant prep
// ---------------------------------------------------------------------------
__global__ __launch_bounds__(128) void bn_prep(const float* __restrict__ gamma,
                                               const float* __restrict__ beta,
                                               const float* __restrict__ rmean,
                                               const float* __restrict__ rvar,
                                               float* __restrict__ scale,
                                               float* __restrict__ shift) {
    int c = threadIdx.x;
    float s = gamma[c] * rsqrtf(rvar[c] + BN_EPS);
    scale[c] = s;
    shift[c] = beta[c] - rmean[c] * s;
}

// ---------------------------------------------------------------------------
// one-time: WT[n*128+k] = bf16(W[k*128+n])   (pre-transposed B for MFMA)
// ---------------------------------------------------------------------------
__global__ __launch_bounds__(256) void w_to_bf16T(const float* __restrict__ W,
                                                  unsigned short* __restrict__ WT) {
    int idx = blockIdx.x * 256 + threadIdx.x;  // 16384 total
    int k = idx >> 7, n = idx & 127;
    WT[n * 128 + k] = f2bf(W[idx]);
}

// ---------------------------------------------------------------------------
// CSR build
// ---------------------------------------------------------------------------
__global__ __launch_bounds__(256) void count_deg(const int* __restrict__ dst,
                                                 int* __restrict__ deg, int E) {
    int i = blockIdx.x * 256 + threadIdx.x;
    if (i < E) atomicAdd(&deg[dst[i]], 1);
}

__global__ __launch_bounds__(1024) void scan_offsets(const int* __restrict__ deg,
                                                     int* __restrict__ off, int N) {
    __shared__ int sums[1024];
    int tid = threadIdx.x;
    int chunk = (N + 1023) / 1024;
    int start = tid * chunk;
    int end = start + chunk; if (end > N) end = N;
    int s = 0;
    for (int i = start; i < end; ++i) s += deg[i];
    sums[tid] = s;
    __syncthreads();
    for (int d = 1; d < 1024; d <<= 1) {
        int v = (tid >= d) ? sums[tid - d] : 0;
        __syncthreads();
        sums[tid] += v;
        __syncthreads();
    }
    int run = (tid == 0) ? 0 : sums[tid - 1];
    for (int i = start; i < end; ++i) { off[i] = run; run += deg[i]; }
    if (tid == 1023) off[N] = run;
}

__global__ __launch_bounds__(256) void fill_csr(const int* __restrict__ src,
                                                const int* __restrict__ dst,
                                                const int* __restrict__ off,
                                                int* __restrict__ cursor,
                                                int* __restrict__ csr_src, int E) {
    int i = blockIdx.x * 256 + threadIdx.x;
    if (i < E) {
        int d = dst[i];
        int p = atomicAdd(&cursor[d], 1);
        csr_src[off[d] + p] = src[i];
    }
}

// ---------------------------------------------------------------------------
// H = X @ W  via MFMA bf16 (fp32 accum), with node_scores fused in epilogue:
// s_src[n] = h[n,:]·a_src ; s_dst[n] = h[n,:]·a_dst
// 128 rows/block, 4 waves × 2 M-tiles × 8 N-tiles, 16x16x32 bf16.
// ---------------------------------------------------------------------------
#define LP_RS 136  // LDS row stride in bf16 elements (272 bytes)

__global__ __launch_bounds__(256) void gemm_mfma(
    const float* __restrict__ X,
    const unsigned short* __restrict__ WT,  // [n][k] bf16 (pre-transposed)
    const float* __restrict__ a_src, const float* __restrict__ a_dst,
    float* __restrict__ H,
    float* __restrict__ s_src, float* __restrict__ s_dst, int N)
{
    __shared__ unsigned short sA[128 * LP_RS];
    __shared__ unsigned short sW[128 * LP_RS];
    int tid = threadIdx.x;
    int r0 = blockIdx.x * 128;

#pragma unroll
    for (int it = 0; it < 8; ++it) {
        int idx = it * 2048 + tid * 8;
        int n = idx >> 7, k = idx & 127;
        *(short8*)&sW[n * LP_RS + k] = *(const short8*)&WT[idx];
    }
#pragma unroll
    for (int it = 0; it < 16; ++it) {
        int r = it * 8 + (tid >> 5);
        int c = (tid & 31) * 4;
        int row = r0 + r;
        float4 x = make_float4(0.f, 0.f, 0.f, 0.f);
        if (row < N) x = *(const float4*)&X[(size_t)row * 128 + c];
        ushort4 u;
        u.x = f2bf(x.x); u.y = f2bf(x.y); u.z = f2bf(x.z); u.w = f2bf(x.w);
        *(ushort4*)&sA[r * LP_RS + c] = u;
    }
    __syncthreads();

    int wave = tid >> 6, lane = tid & 63;
    int ln = lane & 15, quad = lane >> 4;
    int rowbase = wave * 32;

    short8 af[2][4];
#pragma unroll
    for (int m = 0; m < 2; ++m)
#pragma unroll
        for (int kt = 0; kt < 4; ++kt)
            af[m][kt] = *(const short8*)&sA[(rowbase + m * 16 + ln) * LP_RS + kt * 32 + quad * 8];

    float4v acc[2][8];
#pragma unroll
    for (int m = 0; m < 2; ++m)
#pragma unroll
        for (int n = 0; n < 8; ++n)
            acc[m][n] = float4v{0.f, 0.f, 0.f, 0.f};

#pragma unroll
    for (int n = 0; n < 8; ++n) {
#pragma unroll
        for (int kt = 0; kt < 4; ++kt) {
            short8 bf = *(const short8*)&sW[(n * 16 + ln) * LP_RS + kt * 32 + quad * 8];
            acc[0][n] = __builtin_amdgcn_mfma_f32_16x16x32_bf16(af[0][kt], bf, acc[0][n], 0, 0, 0);
            acc[1][n] = __builtin_amdgcn_mfma_f32_16x16x32_bf16(af[1][kt], bf, acc[1][n], 0, 0, 0);
        }
    }

    // epilogue: store H (C/D layout: col=ln, row=quad*4+reg) + fused scores
    float asr[8], adr[8];
#pragma unroll
    for (int n = 0; n < 8; ++n) {
        asr[n] = a_src[n * 16 + ln];
        adr[n] = a_dst[n * 16 + ln];
    }
#pragma unroll
    for (int m = 0; m < 2; ++m) {
        int rb = r0 + rowbase + m * 16 + quad * 4;
#pragma unroll
        for (int n = 0; n < 8; ++n) {
            int col = n * 16 + ln;
            float4v a = acc[m][n];
            if (rb + 0 < N) H[(size_t)(rb + 0) * 128 + col] = a[0];
            if (rb + 1 < N) H[(size_t)(rb + 1) * 128 + col] = a[1];
            if (rb + 2 < N) H[(size_t)(rb + 2) * 128 + col] = a[2];
            if (rb + 3 < N) H[(size_t)(rb + 3) * 128 + col] = a[3];
        }
#pragma unroll
        for (int r = 0; r < 4; ++r) {
            float ps = 0.f, pd = 0.f;
#pragma unroll
            for (int n = 0; n < 8; ++n) {
                float v = acc[m][n][r];
                ps = fmaf(v, asr[n], ps);
                pd = fmaf(v, adr[n], pd);
            }
#pragma unroll
            for (int o = 1; o < 16; o <<= 1) {
                ps += __shfl_xor(ps, o);
                pd += __shfl_xor(pd, o);
            }
            int row = rb + r;
            if (ln == 0 && row < N) { s_src[row] = ps; s_dst[row] = pd; }
        }
    }
}

// ---------------------------------------------------------------------------
// Per-edge softmax weights, quad (16 lanes) per node:
// we[i] = exp(leaky(s_src[csr[i]]+s_dst[node]) - m_node); invd[node]=1/(sum+eps)
// ---------------------------------------------------------------------------
__global__ __launch_bounds__(256) void edge_softmax(const int* __restrict__ off,
                                                    const int* __restrict__ csr,
                                                    const float* __restrict__ s_src,
                                                    const float* __restrict__ s_dst,
                                                    float* __restrict__ we,
                                                    float* __restrict__ invd, int N) {
    int tid = threadIdx.x;
    int node = blockIdx.x * 16 + (tid >> 4);
    if (node >= N) return;
    int ln = tid & 15;
    int beg = off[node], end = off[node + 1];
    float sd = s_dst[node];

    float m = -INFINITY;
    for (int i = beg + ln; i < end; i += 16) {
        float e = s_src[csr[i]] + sd;
        e = (e >= 0.f) ? e : NEG_SLOPE * e;
        we[i] = e;
        m = fmaxf(m, e);
    }
#pragma unroll
    for (int o = 8; o; o >>= 1) m = fmaxf(m, __shfl_xor(m, o));

    float sw = 0.f;
    for (int i = beg + ln; i < end; i += 16) {
        float w = expf(we[i] - m);
        we[i] = w;
        sw += w;
    }
#pragma unroll
    for (int o = 8; o; o >>= 1) sw += __shfl_xor(sw, o);
    if (ln == 0) invd[node] = 1.f / (sw + 1e-16f);
}

// ---------------------------------------------------------------------------
// Weighted gather: out[n,:] = (sum_e we[e]*H[src_e,:])*invd[n] + bias (+BN/ReLU)
// One wave per node, lanes = 2 channels; 4-edge unroll for MLP.
// ---------------------------------------------------------------------------
__global__ __launch_bounds__(256) void gat_gather(const float* __restrict__ H,
                                                  const int* __restrict__ off,
                                                  const int* __restrict__ csr,
                                                  const float* __restrict__ we,
                                                  const float* __restrict__ invd,
                                                  const float* __restrict__ bias,
                                                  const float* __restrict__ bn_scale,
                                                  const float* __restrict__ bn_shift,
                                                  int do_bn_relu,
                                                  float* __restrict__ out, int N) {
    int node = blockIdx.x * 4 + (threadIdx.x >> 6);
    if (node >= N) return;
    int lane = threadIdx.x & 63;
    int c0 = lane * 2;
    int beg = off[node], end = off[node + 1];
    float inv = invd[node];

    float accx = 0.f, accy = 0.f;
    int i = beg;
    for (; i + 4 <= end; i += 4) {
        int s0 = csr[i + 0], s1 = csr[i + 1], s2 = csr[i + 2], s3 = csr[i + 3];
        float w0 = we[i + 0], w1 = we[i + 1], w2 = we[i + 2], w3 = we[i + 3];
        float2 h0 = *(const float2*)&H[(size_t)s0 * 128 + c0];
        float2 h1 = *(const float2*)&H[(size_t)s1 * 128 + c0];
        float2 h2 = *(const float2*)&H[(size_t)s2 * 128 + c0];
        float2 h3 = *(const float2*)&H[(size_t)s3 * 128 + c0];
        accx = fmaf(w0, h0.x, accx); accy = fmaf(w0, h0.y, accy);
        accx = fmaf(w1, h1.x, accx); accy = fmaf(w1, h1.y, accy);
        accx = fmaf(w2, h2.x, accx); accy = fmaf(w2, h2.y, accy);
        accx = fmaf(w3, h3.x, accx); accy = fmaf(w3, h3.y, accy);
    }
    for (; i < end; ++i) {
        int s = csr[i];
        float w = we[i];
        float2 hv = *(const float2*)&H[(size_t)s * 128 + c0];
        accx = fmaf(w, hv.x, accx);
        accy = fmaf(w, hv.y, accy);
    }
    float o0 = accx * inv + bias[c0];
    float o1 = accy * inv + bias[c0 + 1];
    if (do_bn_relu) {
        o0 = fmaxf(o0 * bn_scale[c0] + bn_shift[c0], 0.f);
        o1 = fmaxf(o1 * bn_scale[c0 + 1] + bn_shift[c0 + 1], 0.f);
    }
    out[(size_t)node * 128 + c0] = o0;
    out[(size_t)node * 128 + c0 + 1] = o1;
}

// ---------------------------------------------------------------------------
// Link predictor, MFMA bf16 (validated R1)
// ---------------------------------------------------------------------------
__global__ __launch_bounds__(256) void link_pred_mfma(
    const float* __restrict__ X,
    const int* __restrict__ E0, const int* __restrict__ E1,
    const unsigned short* __restrict__ WTg,  // [128][128] bf16, WTg[n][k]
    const float* __restrict__ bp1,
    const float* __restrict__ Wp2,
    const float* __restrict__ bp2_p,
    float* __restrict__ out, int Q)
{
    __shared__ unsigned short sA[128 * LP_RS];
    __shared__ unsigned short sW[128 * LP_RS];
    int tid = threadIdx.x;
    int q0 = blockIdx.x * 128;

#pragma unroll
    for (int it = 0; it < 8; ++it) {
        int idx = it * 2048 + tid * 8;
        int n = idx >> 7, k = idx & 127;
        *(short8*)&sW[n * LP_RS + k] = *(const short8*)&WTg[idx];
    }
#pragma unroll
    for (int it = 0; it < 16; ++it) {
        int r = it * 8 + (tid >> 5);
        int c = (tid & 31) * 4;
        int q = q0 + r;
        float4 p = make_float4(0.f, 0.f, 0.f, 0.f);
        if (q < Q) {
            int a = E0[q], b = E1[q];
            float4 xa = *(const float4*)&X[(size_t)a * 128 + c];
            float4 xb = *(const float4*)&X[(size_t)b * 128 + c];
            p.x = xa.x * xb.x; p.y = xa.y * xb.y;
            p.z = xa.z * xb.z; p.w = xa.w * xb.w;
        }
        ushort4 u;
        u.x = f2bf(p.x); u.y = f2bf(p.y); u.z = f2bf(p.z); u.w = f2bf(p.w);
        *(ushort4*)&sA[r * LP_RS + c] = u;
    }
    __syncthreads();

    int wave = tid >> 6, lane = tid & 63;
    int ln = lane & 15, quad = lane >> 4;
    int rowbase = wave * 32;

    short8 af[2][4];
#pragma unroll
    for (int m = 0; m < 2; ++m)
#pragma unroll
        for (int kt = 0; kt < 4; ++kt)
            af[m][kt] = *(const short8*)&sA[(rowbase + m * 16 + ln) * LP_RS + kt * 32 + quad * 8];

    float bias[8], w2c[8];
#pragma unroll
    for (int n = 0; n < 8; ++n) {
        bias[n] = bp1[n * 16 + ln];
        w2c[n] = Wp2[n * 16 + ln];
    }

    float4v acc[2][8];
#pragma unroll
    for (int m = 0; m < 2; ++m)
#pragma unroll
        for (int n = 0; n < 8; ++n)
            acc[m][n] = float4v{bias[n], bias[n], bias[n], bias[n]};

#pragma unroll
    for (int n = 0; n < 8; ++n) {
#pragma unroll
        for (int kt = 0; kt < 4; ++kt) {
            short8 bf = *(const short8*)&sW[(n * 16 + ln) * LP_RS + kt * 32 + quad * 8];
            acc[0][n] = __builtin_amdgcn_mfma_f32_16x16x32_bf16(af[0][kt], bf, acc[0][n], 0, 0, 0);
            acc[1][n] = __builtin_amdgcn_mfma_f32_16x16x32_bf16(af[1][kt], bf, acc[1][n], 0, 0, 0);
        }
    }

    float b2 = bp2_p[0];
#pragma unroll
    for (int m = 0; m < 2; ++m) {
        float r0 = 0.f, r1 = 0.f, r2 = 0.f, r3 = 0.f;
#pragma unroll
        for (int n = 0; n < 8; ++n) {
            float4v a = acc[m][n];
            float w = w2c[n];
            r0 += fmaxf(a.x, 0.f) * w;
            r1 += fmaxf(a.y, 0.f) * w;
            r2 += fmaxf(a.z, 0.f) * w;
            r3 += fmaxf(a.w, 0.f) * w;
        }
#pragma unroll
        for (int o = 1; o < 16; o <<= 1) {
            r0 += __shfl_xor(r0, o);
            r1 += __shfl_xor(r1, o);
            r2 += __shfl_xor(r2, o);
            r3 += __shfl_xor(r3, o);
        }
        if (ln == 0) {
            int rbase = q0 + rowbase + m * 16 + quad * 4;
            float rv[4] = {r0, r1, r2, r3};
#pragma unroll
            for (int r = 0; r < 4; ++r) {
                int q = rbase + r;
                if (q < Q) out[q] = 1.f / (1.f + expf(-(rv[r] + b2)));
            }
        }
    }
}

// ---------------------------------------------------------------------------
extern "C" void kernel_launch(void* const* d_in, const int* in_sizes, int n_in,
                              void* d_out, int out_size, void* d_ws, size_t ws_size,
                              hipStream_t stream) {
    const float* emb    = (const float*)d_in[0];
    const float* W1     = (const float*)d_in[1];
    const float* a_src1 = (const float*)d_in[2];
    const float* a_dst1 = (const float*)d_in[3];
    const float* b1     = (const float*)d_in[4];
    const float* gamma  = (const float*)d_in[5];
    const float* beta   = (const float*)d_in[6];
    const float* rmean  = (const float*)d_in[7];
    const float* rvar   = (const float*)d_in[8];
    const float* W2     = (const float*)d_in[9];
    const float* a_src2 = (const float*)d_in[10];
    const float* a_dst2 = (const float*)d_in[11];
    const float* b2     = (const float*)d_in[12];
    const float* Wp1    = (const float*)d_in[13];
    const float* bp1    = (const float*)d_in[14];
    const float* Wp2    = (const float*)d_in[15];
    const float* bp2    = (const float*)d_in[16];
    const int* edge_index = (const int*)d_in[17];
    const int* edges      = (const int*)d_in[18];

    const int N = in_sizes[0] / 128;
    const int E = in_sizes[17] / 2;
    const int Q = in_sizes[18] / 2;
    const int* src = edge_index;
    const int* dst = edge_index + E;
    const int* e0 = edges;
    const int* e1 = edges + Q;
    float* out = (float*)d_out;

    uintptr_t base = (uintptr_t)d_ws;
    size_t cur = 0;
    auto take = [&](size_t bytes) -> void* {
        void* p = (void*)(base + cur);
        cur += (bytes + 255) & ~(size_t)255;
        return p;
    };
    float* bufA   = (float*)take((size_t)N * 128 * 4);
    float* bufB   = (float*)take((size_t)N * 128 * 4);
    float* s_src  = (float*)take((size_t)N * 4);
    float* s_dst  = (float*)take((size_t)N * 4);
    float* bnsc   = (float*)take(128 * 4);
    float* bnsh   = (float*)take(128 * 4);
    int*   deg    = (int*)take((size_t)N * 4);
    int*   cursor = (int*)take((size_t)N * 4);
    int*   offs   = (int*)take((size_t)(N + 1) * 4);
    int*   csr    = (int*)take((size_t)E * 4);
    float* we     = (float*)take((size_t)E * 4);
    float* invd   = (float*)take((size_t)N * 4);
    unsigned short* wt1 = (unsigned short*)take(128 * 128 * 2);
    unsigned short* wt2 = (unsigned short*)take(128 * 128 * 2);
    unsigned short* wtp = (unsigned short*)take(128 * 128 * 2);
    (void)ws_size; (void)n_in; (void)out_size;

    hipMemsetAsync(deg, 0, (size_t)N * 4, stream);
    hipMemsetAsync(cursor, 0, (size_t)N * 4, stream);

    bn_prep<<<1, 128, 0, stream>>>(gamma, beta, rmean, rvar, bnsc, bnsh);
    w_to_bf16T<<<64, 256, 0, stream>>>(W1, wt1);
    w_to_bf16T<<<64, 256, 0, stream>>>(W2, wt2);
    w_to_bf16T<<<64, 256, 0, stream>>>(Wp1, wtp);

    count_deg<<<(E + 255) / 256, 256, 0, stream>>>(dst, deg, E);
    scan_offsets<<<1, 1024, 0, stream>>>(deg, offs, N);
    fill_csr<<<(E + 255) / 256, 256, 0, stream>>>(src, dst, offs, cursor, csr, E);

    int gblk = (N + 127) / 128;
    // ---- conv1 + BN + ReLU ----
    gemm_mfma<<<gblk, 256, 0, stream>>>(emb, wt1, a_src1, a_dst1, bufA, s_src, s_dst, N);
    edge_softmax<<<(N + 15) / 16, 256, 0, stream>>>(offs, csr, s_src, s_dst, we, invd, N);
    gat_gather<<<(N + 3) / 4, 256, 0, stream>>>(bufA, offs, csr, we, invd, b1,
                                                bnsc, bnsh, 1, bufB, N);
    // ---- conv2 ----
    gemm_mfma<<<gblk, 256, 0, stream>>>(bufB, wt2, a_src2, a_dst2, bufA, s_src, s_dst, N);
    edge_softmax<<<(N + 15) / 16, 256, 0, stream>>>(offs, csr, s_src, s_dst, we, invd, N);
    gat_gather<<<(N + 3) / 4, 256, 0, stream>>>(bufA, offs, csr, we, invd, b2,
                                                nullptr, nullptr, 0, bufB, N);
    // ---- link predictor (MFMA bf16) ----
    link_pred_mfma<<<(Q + 127) / 128, 256, 0, stream>>>(bufB, e0, e1, wtp, bp1, Wp2, bp2, out, Q);
}

// Round 4
// 417.314 us; speedup vs baseline: 2.0728x; 1.1783x over previous
//
#include <hip/hip_runtime.h>
#include <hip/hip_bf16.h>
#include <math.h>
#include <stdint.h>

#define NEG_SLOPE 0.2f
#define BN_EPS 1e-5f

typedef __attribute__((ext_vector_type(8))) short short8;
typedef __attribute__((ext_vector_type(4))) float float4v;

static __device__ __forceinline__ unsigned short f2bf(float f) {
    union { float f; unsigned u; } v; v.f = f;
    unsigned r = (v.u + 0x7fffu + ((v.u >> 16) & 1u)) >> 16;  // RNE
    return (unsigned short)r;
}

// ---------------------------------------------------------------------------
// BN constant prep
// ---------------------------------------------------------------------------
__global__ __launch_bounds__(128) void bn_prep(const float* __restrict__ gamma,
                                               const float* __restrict__ beta,
                                               const float* __restrict__ rmean,
                                               const float* __restrict__ rvar,
                                               float* __restrict__ scale,
                                               float* __restrict__ shift) {
    int c = threadIdx.x;
    float s = gamma[c] * rsqrtf(rvar[c] + BN_EPS);
    scale[c] = s;
    shift[c] = beta[c] - rmean[c] * s;
}

// ---------------------------------------------------------------------------
// one-time: WT[n*128+k] = bf16(W[k*128+n])   (pre-transposed B for MFMA)
// ---------------------------------------------------------------------------
__global__ __launch_bounds__(256) void w_to_bf16T(const float* __restrict__ W,
                                                  unsigned short* __restrict__ WT) {
    int idx = blockIdx.x * 256 + threadIdx.x;  // 16384 total
    int k = idx >> 7, n = idx & 127;
    WT[n * 128 + k] = f2bf(W[idx]);
}

// ---------------------------------------------------------------------------
// CSR build
// ---------------------------------------------------------------------------
__global__ __launch_bounds__(256) void count_deg(const int* __restrict__ dst,
                                                 int* __restrict__ deg, int E) {
    int i = blockIdx.x * 256 + threadIdx.x;
    if (i < E) atomicAdd(&deg[dst[i]], 1);
}

// 3-phase parallel exclusive scan of deg[N] -> offs[N+1]
// phase 1: per-block (256 elems) sums
__global__ __launch_bounds__(256) void scan_block_reduce(const int* __restrict__ deg,
                                                         int* __restrict__ bsum, int N) {
    __shared__ int s[256];
    int t = threadIdx.x;
    int i = blockIdx.x * 256 + t;
    s[t] = (i < N) ? deg[i] : 0;
    __syncthreads();
#pragma unroll
    for (int d = 128; d; d >>= 1) {
        if (t < d) s[t] += s[t + d];
        __syncthreads();
    }
    if (t == 0) bsum[blockIdx.x] = s[0];
}

// phase 2: one block scans <=1024 block sums in place (exclusive), writes offs[N]
__global__ __launch_bounds__(1024) void scan_block_sums(int* __restrict__ bsum,
                                                        int* __restrict__ offs,
                                                        int nb, int N) {
    __shared__ int s[1024];
    int t = threadIdx.x;
    int v = (t < nb) ? bsum[t] : 0;
    s[t] = v;
    __syncthreads();
    for (int d = 1; d < 1024; d <<= 1) {
        int u = (t >= d) ? s[t - d] : 0;
        __syncthreads();
        s[t] += u;
        __syncthreads();
    }
    if (t < nb) bsum[t] = s[t] - v;       // exclusive block base
    if (t == 1023) offs[N] = s[1023];     // total == E
}

// phase 3: in-block exclusive scan + block base -> offs[i]
__global__ __launch_bounds__(256) void scan_write_offsets(const int* __restrict__ deg,
                                                          const int* __restrict__ bsum,
                                                          int* __restrict__ offs, int N) {
    __shared__ int s[256];
    int t = threadIdx.x;
    int i = blockIdx.x * 256 + t;
    int v = (i < N) ? deg[i] : 0;
    s[t] = v;
    __syncthreads();
    for (int d = 1; d < 256; d <<= 1) {
        int u = (t >= d) ? s[t - d] : 0;
        __syncthreads();
        s[t] += u;
        __syncthreads();
    }
    if (i < N) offs[i] = bsum[blockIdx.x] + s[t] - v;
}

__global__ __launch_bounds__(256) void fill_csr(const int* __restrict__ src,
                                                const int* __restrict__ dst,
                                                const int* __restrict__ off,
                                                int* __restrict__ cursor,
                                                int* __restrict__ csr_src, int E) {
    int i = blockIdx.x * 256 + threadIdx.x;
    if (i < E) {
        int d = dst[i];
        int p = atomicAdd(&cursor[d], 1);
        csr_src[off[d] + p] = src[i];
    }
}

// ---------------------------------------------------------------------------
// H = X @ W  via MFMA bf16 (fp32 accum), node_scores fused in epilogue
// ---------------------------------------------------------------------------
#define LP_RS 136  // LDS row stride in bf16 elements (272 bytes)

__global__ __launch_bounds__(256) void gemm_mfma(
    const float* __restrict__ X,
    const unsigned short* __restrict__ WT,  // [n][k] bf16 (pre-transposed)
    const float* __restrict__ a_src, const float* __restrict__ a_dst,
    float* __restrict__ H,
    float* __restrict__ s_src, float* __restrict__ s_dst, int N)
{
    __shared__ unsigned short sA[128 * LP_RS];
    __shared__ unsigned short sW[128 * LP_RS];
    int tid = threadIdx.x;
    int r0 = blockIdx.x * 128;

#pragma unroll
    for (int it = 0; it < 8; ++it) {
        int idx = it * 2048 + tid * 8;
        int n = idx >> 7, k = idx & 127;
        *(short8*)&sW[n * LP_RS + k] = *(const short8*)&WT[idx];
    }
#pragma unroll
    for (int it = 0; it < 16; ++it) {
        int r = it * 8 + (tid >> 5);
        int c = (tid & 31) * 4;
        int row = r0 + r;
        float4 x = make_float4(0.f, 0.f, 0.f, 0.f);
        if (row < N) x = *(const float4*)&X[(size_t)row * 128 + c];
        ushort4 u;
        u.x = f2bf(x.x); u.y = f2bf(x.y); u.z = f2bf(x.z); u.w = f2bf(x.w);
        *(ushort4*)&sA[r * LP_RS + c] = u;
    }
    __syncthreads();

    int wave = tid >> 6, lane = tid & 63;
    int ln = lane & 15, quad = lane >> 4;
    int rowbase = wave * 32;

    short8 af[2][4];
#pragma unroll
    for (int m = 0; m < 2; ++m)
#pragma unroll
        for (int kt = 0; kt < 4; ++kt)
            af[m][kt] = *(const short8*)&sA[(rowbase + m * 16 + ln) * LP_RS + kt * 32 + quad * 8];

    float4v acc[2][8];
#pragma unroll
    for (int m = 0; m < 2; ++m)
#pragma unroll
        for (int n = 0; n < 8; ++n)
            acc[m][n] = float4v{0.f, 0.f, 0.f, 0.f};

#pragma unroll
    for (int n = 0; n < 8; ++n) {
#pragma unroll
        for (int kt = 0; kt < 4; ++kt) {
            short8 bf = *(const short8*)&sW[(n * 16 + ln) * LP_RS + kt * 32 + quad * 8];
            acc[0][n] = __builtin_amdgcn_mfma_f32_16x16x32_bf16(af[0][kt], bf, acc[0][n], 0, 0, 0);
            acc[1][n] = __builtin_amdgcn_mfma_f32_16x16x32_bf16(af[1][kt], bf, acc[1][n], 0, 0, 0);
        }
    }

    float asr[8], adr[8];
#pragma unroll
    for (int n = 0; n < 8; ++n) {
        asr[n] = a_src[n * 16 + ln];
        adr[n] = a_dst[n * 16 + ln];
    }
#pragma unroll
    for (int m = 0; m < 2; ++m) {
        int rb = r0 + rowbase + m * 16 + quad * 4;
#pragma unroll
        for (int n = 0; n < 8; ++n) {
            int col = n * 16 + ln;
            float4v a = acc[m][n];
            if (rb + 0 < N) H[(size_t)(rb + 0) * 128 + col] = a[0];
            if (rb + 1 < N) H[(size_t)(rb + 1) * 128 + col] = a[1];
            if (rb + 2 < N) H[(size_t)(rb + 2) * 128 + col] = a[2];
            if (rb + 3 < N) H[(size_t)(rb + 3) * 128 + col] = a[3];
        }
#pragma unroll
        for (int r = 0; r < 4; ++r) {
            float ps = 0.f, pd = 0.f;
#pragma unroll
            for (int n = 0; n < 8; ++n) {
                float v = acc[m][n][r];
                ps = fmaf(v, asr[n], ps);
                pd = fmaf(v, adr[n], pd);
            }
#pragma unroll
            for (int o = 1; o < 16; o <<= 1) {
                ps += __shfl_xor(ps, o);
                pd += __shfl_xor(pd, o);
            }
            int row = rb + r;
            if (ln == 0 && row < N) { s_src[row] = ps; s_dst[row] = pd; }
        }
    }
}

// ---------------------------------------------------------------------------
// Per-edge softmax weights, quad (16 lanes) per node
// ---------------------------------------------------------------------------
__global__ __launch_bounds__(256) void edge_softmax(const int* __restrict__ off,
                                                    const int* __restrict__ csr,
                                                    const float* __restrict__ s_src,
                                                    const float* __restrict__ s_dst,
                                                    float* __restrict__ we,
                                                    float* __restrict__ invd, int N) {
    int tid = threadIdx.x;
    int node = blockIdx.x * 16 + (tid >> 4);
    if (node >= N) return;
    int ln = tid & 15;
    int beg = off[node], end = off[node + 1];
    float sd = s_dst[node];

    float m = -INFINITY;
    for (int i = beg + ln; i < end; i += 16) {
        float e = s_src[csr[i]] + sd;
        e = (e >= 0.f) ? e : NEG_SLOPE * e;
        we[i] = e;
        m = fmaxf(m, e);
    }
#pragma unroll
    for (int o = 8; o; o >>= 1) m = fmaxf(m, __shfl_xor(m, o));

    float sw = 0.f;
    for (int i = beg + ln; i < end; i += 16) {
        float w = expf(we[i] - m);
        we[i] = w;
        sw += w;
    }
#pragma unroll
    for (int o = 8; o; o >>= 1) sw += __shfl_xor(sw, o);
    if (ln == 0) invd[node] = 1.f / (sw + 1e-16f);
}

// ---------------------------------------------------------------------------
// Weighted gather: out[n,:] = (sum_e we[e]*H[src_e,:])*invd[n] + bias (+BN/ReLU)
// ---------------------------------------------------------------------------
__global__ __launch_bounds__(256) void gat_gather(const float* __restrict__ H,
                                                  const int* __restrict__ off,
                                                  const int* __restrict__ csr,
                                                  const float* __restrict__ we,
                                                  const float* __restrict__ invd,
                                                  const float* __restrict__ bias,
                                                  const float* __restrict__ bn_scale,
                                                  const float* __restrict__ bn_shift,
                                                  int do_bn_relu,
                                                  float* __restrict__ out, int N) {
    int node = blockIdx.x * 4 + (threadIdx.x >> 6);
    if (node >= N) return;
    int lane = threadIdx.x & 63;
    int c0 = lane * 2;
    int beg = off[node], end = off[node + 1];
    float inv = invd[node];

    float accx = 0.f, accy = 0.f;
    int i = beg;
    for (; i + 4 <= end; i += 4) {
        int s0 = csr[i + 0], s1 = csr[i + 1], s2 = csr[i + 2], s3 = csr[i + 3];
        float w0 = we[i + 0], w1 = we[i + 1], w2 = we[i + 2], w3 = we[i + 3];
        float2 h0 = *(const float2*)&H[(size_t)s0 * 128 + c0];
        float2 h1 = *(const float2*)&H[(size_t)s1 * 128 + c0];
        float2 h2 = *(const float2*)&H[(size_t)s2 * 128 + c0];
        float2 h3 = *(const float2*)&H[(size_t)s3 * 128 + c0];
        accx = fmaf(w0, h0.x, accx); accy = fmaf(w0, h0.y, accy);
        accx = fmaf(w1, h1.x, accx); accy = fmaf(w1, h1.y, accy);
        accx = fmaf(w2, h2.x, accx); accy = fmaf(w2, h2.y, accy);
        accx = fmaf(w3, h3.x, accx); accy = fmaf(w3, h3.y, accy);
    }
    for (; i < end; ++i) {
        int s = csr[i];
        float w = we[i];
        float2 hv = *(const float2*)&H[(size_t)s * 128 + c0];
        accx = fmaf(w, hv.x, accx);
        accy = fmaf(w, hv.y, accy);
    }
    float o0 = accx * inv + bias[c0];
    float o1 = accy * inv + bias[c0 + 1];
    if (do_bn_relu) {
        o0 = fmaxf(o0 * bn_scale[c0] + bn_shift[c0], 0.f);
        o1 = fmaxf(o1 * bn_scale[c0 + 1] + bn_shift[c0 + 1], 0.f);
    }
    out[(size_t)node * 128 + c0] = o0;
    out[(size_t)node * 128 + c0 + 1] = o1;
}

// ---------------------------------------------------------------------------
// Link predictor, MFMA bf16 (validated R1)
// ---------------------------------------------------------------------------
__global__ __launch_bounds__(256) void link_pred_mfma(
    const float* __restrict__ X,
    const int* __restrict__ E0, const int* __restrict__ E1,
    const unsigned short* __restrict__ WTg,  // [128][128] bf16, WTg[n][k]
    const float* __restrict__ bp1,
    const float* __restrict__ Wp2,
    const float* __restrict__ bp2_p,
    float* __restrict__ out, int Q)
{
    __shared__ unsigned short sA[128 * LP_RS];
    __shared__ unsigned short sW[128 * LP_RS];
    int tid = threadIdx.x;
    int q0 = blockIdx.x * 128;

#pragma unroll
    for (int it = 0; it < 8; ++it) {
        int idx = it * 2048 + tid * 8;
        int n = idx >> 7, k = idx & 127;
        *(short8*)&sW[n * LP_RS + k] = *(const short8*)&WTg[idx];
    }
#pragma unroll
    for (int it = 0; it < 16; ++it) {
        int r = it * 8 + (tid >> 5);
        int c = (tid & 31) * 4;
        int q = q0 + r;
        float4 p = make_float4(0.f, 0.f, 0.f, 0.f);
        if (q < Q) {
            int a = E0[q], b = E1[q];
            float4 xa = *(const float4*)&X[(size_t)a * 128 + c];
            float4 xb = *(const float4*)&X[(size_t)b * 128 + c];
            p.x = xa.x * xb.x; p.y = xa.y * xb.y;
            p.z = xa.z * xb.z; p.w = xa.w * xb.w;
        }
        ushort4 u;
        u.x = f2bf(p.x); u.y = f2bf(p.y); u.z = f2bf(p.z); u.w = f2bf(p.w);
        *(ushort4*)&sA[r * LP_RS + c] = u;
    }
    __syncthreads();

    int wave = tid >> 6, lane = tid & 63;
    int ln = lane & 15, quad = lane >> 4;
    int rowbase = wave * 32;

    short8 af[2][4];
#pragma unroll
    for (int m = 0; m < 2; ++m)
#pragma unroll
        for (int kt = 0; kt < 4; ++kt)
            af[m][kt] = *(const short8*)&sA[(rowbase + m * 16 + ln) * LP_RS + kt * 32 + quad * 8];

    float bias[8], w2c[8];
#pragma unroll
    for (int n = 0; n < 8; ++n) {
        bias[n] = bp1[n * 16 + ln];
        w2c[n] = Wp2[n * 16 + ln];
    }

    float4v acc[2][8];
#pragma unroll
    for (int m = 0; m < 2; ++m)
#pragma unroll
        for (int n = 0; n < 8; ++n)
            acc[m][n] = float4v{bias[n], bias[n], bias[n], bias[n]};

#pragma unroll
    for (int n = 0; n < 8; ++n) {
#pragma unroll
        for (int kt = 0; kt < 4; ++kt) {
            short8 bf = *(const short8*)&sW[(n * 16 + ln) * LP_RS + kt * 32 + quad * 8];
            acc[0][n] = __builtin_amdgcn_mfma_f32_16x16x32_bf16(af[0][kt], bf, acc[0][n], 0, 0, 0);
            acc[1][n] = __builtin_amdgcn_mfma_f32_16x16x32_bf16(af[1][kt], bf, acc[1][n], 0, 0, 0);
        }
    }

    float b2 = bp2_p[0];
#pragma unroll
    for (int m = 0; m < 2; ++m) {
        float r0 = 0.f, r1 = 0.f, r2 = 0.f, r3 = 0.f;
#pragma unroll
        for (int n = 0; n < 8; ++n) {
            float4v a = acc[m][n];
            float w = w2c[n];
            r0 += fmaxf(a.x, 0.f) * w;
            r1 += fmaxf(a.y, 0.f) * w;
            r2 += fmaxf(a.z, 0.f) * w;
            r3 += fmaxf(a.w, 0.f) * w;
        }
#pragma unroll
        for (int o = 1; o < 16; o <<= 1) {
            r0 += __shfl_xor(r0, o);
            r1 += __shfl_xor(r1, o);
            r2 += __shfl_xor(r2, o);
            r3 += __shfl_xor(r3, o);
        }
        if (ln == 0) {
            int rbase = q0 + rowbase + m * 16 + quad * 4;
            float rv[4] = {r0, r1, r2, r3};
#pragma unroll
            for (int r = 0; r < 4; ++r) {
                int q = rbase + r;
                if (q < Q) out[q] = 1.f / (1.f + expf(-(rv[r] + b2)));
            }
        }
    }
}

// ---------------------------------------------------------------------------
extern "C" void kernel_launch(void* const* d_in, const int* in_sizes, int n_in,
                              void* d_out, int out_size, void* d_ws, size_t ws_size,
                              hipStream_t stream) {
    const float* emb    = (const float*)d_in[0];
    const float* W1     = (const float*)d_in[1];
    const float* a_src1 = (const float*)d_in[2];
    const float* a_dst1 = (const float*)d_in[3];
    const float* b1     = (const float*)d_in[4];
    const float* gamma  = (const float*)d_in[5];
    const float* beta   = (const float*)d_in[6];
    const float* rmean  = (const float*)d_in[7];
    const float* rvar   = (const float*)d_in[8];
    const float* W2     = (const float*)d_in[9];
    const float* a_src2 = (const float*)d_in[10];
    const float* a_dst2 = (const float*)d_in[11];
    const float* b2     = (const float*)d_in[12];
    const float* Wp1    = (const float*)d_in[13];
    const float* bp1    = (const float*)d_in[14];
    const float* Wp2    = (const float*)d_in[15];
    const float* bp2    = (const float*)d_in[16];
    const int* edge_index = (const int*)d_in[17];
    const int* edges      = (const int*)d_in[18];

    const int N = in_sizes[0] / 128;
    const int E = in_sizes[17] / 2;
    const int Q = in_sizes[18] / 2;
    const int* src = edge_index;
    const int* dst = edge_index + E;
    const int* e0 = edges;
    const int* e1 = edges + Q;
    float* out = (float*)d_out;

    uintptr_t base = (uintptr_t)d_ws;
    size_t cur = 0;
    auto take = [&](size_t bytes) -> void* {
        void* p = (void*)(base + cur);
        cur += (bytes + 255) & ~(size_t)255;
        return p;
    };
    float* bufA   = (float*)take((size_t)N * 128 * 4);
    float* bufB   = (float*)take((size_t)N * 128 * 4);
    float* s_src  = (float*)take((size_t)N * 4);
    float* s_dst  = (float*)take((size_t)N * 4);
    float* bnsc   = (float*)take(128 * 4);
    float* bnsh   = (float*)take(128 * 4);
    int*   deg    = (int*)take((size_t)N * 4);
    int*   cursor = (int*)take((size_t)N * 4);
    int*   offs   = (int*)take((size_t)(N + 1) * 4);
    int*   csr    = (int*)take((size_t)E * 4);
    float* we     = (float*)take((size_t)E * 4);
    float* invd   = (float*)take((size_t)N * 4);
    unsigned short* wt1 = (unsigned short*)take(128 * 128 * 2);
    unsigned short* wt2 = (unsigned short*)take(128 * 128 * 2);
    unsigned short* wtp = (unsigned short*)take(128 * 128 * 2);
    int nb = (N + 255) / 256;  // 196 for N=50000 (must be <=1024)
    int*   bsum   = (int*)take((size_t)nb * 4);
    (void)ws_size; (void)n_in; (void)out_size;

    hipMemsetAsync(deg, 0, (size_t)N * 4, stream);
    hipMemsetAsync(cursor, 0, (size_t)N * 4, stream);

    bn_prep<<<1, 128, 0, stream>>>(gamma, beta, rmean, rvar, bnsc, bnsh);
    w_to_bf16T<<<64, 256, 0, stream>>>(W1, wt1);
    w_to_bf16T<<<64, 256, 0, stream>>>(W2, wt2);
    w_to_bf16T<<<64, 256, 0, stream>>>(Wp1, wtp);

    count_deg<<<(E + 255) / 256, 256, 0, stream>>>(dst, deg, E);
    scan_block_reduce<<<nb, 256, 0, stream>>>(deg, bsum, N);
    scan_block_sums<<<1, 1024, 0, stream>>>(bsum, offs, nb, N);
    scan_write_offsets<<<nb, 256, 0, stream>>>(deg, bsum, offs, N);
    fill_csr<<<(E + 255) / 256, 256, 0, stream>>>(src, dst, offs, cursor, csr, E);

    int gblk = (N + 127) / 128;
    // ---- conv1 + BN + ReLU ----
    gemm_mfma<<<gblk, 256, 0, stream>>>(emb, wt1, a_src1, a_dst1, bufA, s_src, s_dst, N);
    edge_softmax<<<(N + 15) / 16, 256, 0, stream>>>(offs, csr, s_src, s_dst, we, invd, N);
    gat_gather<<<(N + 3) / 4, 256, 0, stream>>>(bufA, offs, csr, we, invd, b1,
                                                bnsc, bnsh, 1, bufB, N);
    // ---- conv2 ----
    gemm_mfma<<<gblk, 256, 0, stream>>>(bufB, wt2, a_src2, a_dst2, bufA, s_src, s_dst, N);
    edge_softmax<<<(N + 15) / 16, 256, 0, stream>>>(offs, csr, s_src, s_dst, we, invd, N);
    gat_gather<<<(N + 3) / 4, 256, 0, stream>>>(bufA, offs, csr, we, invd, b2,
                                                nullptr, nullptr, 0, bufB, N);
    // ---- link predictor (MFMA bf16) ----
    link_pred_mfma<<<(Q + 127) / 128, 256, 0, stream>>>(bufB, e0, e1, wtp, bp1, Wp2, bp2, out, Q);
}